// Round 7
// baseline (26.807 us; speedup 1.0000x reference)
//
#include <hip/hip_runtime.h>

// PresetEmbedding: N=2048, L=256, H=64, NT=16, MAXC=32
// out[n][l][h] = (t>=8) ? cat_table[t*32 + round(cat_val)][h]
//                       : num_val * conv_w[t*64+h] + conv_b[t*64+h]
// t = l % 16 (deterministic from index), cat_val = u_in[n][l][0],
// num_val = u_in[n][l][1].
//
// v7: two float4s per thread at stride TOTAL/2 (same type t for both ->
// conv_w/conv_b loads shared across both stores for num waves), 1024-thread
// blocks (4096 workgroups, 8x fewer dispatches), wave-uniform scalar u_in
// loads for both streams. Plain stores (NT regressed 48% in R3).

#define N_ 2048
#define L_ 256
#define H_ 64

#define TOTAL_V4 (N_ * L_ * (H_ / 4))   // 8,388,608 float4s
#define HALF_V4  (TOTAL_V4 / 2)         // 4,194,304
#define PAIR_OFF (HALF_V4 >> 4)         // 262,144 pairs (multiple of 16 -> same t)

typedef float f32x4 __attribute__((ext_vector_type(4)));

__global__ __launch_bounds__(1024) void preset_embed_kernel(
    const float* __restrict__ u_in,      // N*L*3
    const float* __restrict__ conv_w,    // NT*H = 1024
    const float* __restrict__ conv_b,    // NT*H = 1024
    const float* __restrict__ cat_table, // MAXC*NT*H = 512*64
    float* __restrict__ out)             // N*L*H
{
    const int i     = blockIdx.x * 1024 + threadIdx.x;  // stream-1 float4 index
    const int lane4 = i & 15;                 // float4 within H=64
    const int wid   = threadIdx.x >> 6;       // wave id in block, 0..15 (uniform)
    const int pb1   = blockIdx.x * 64 + wid * 4;  // stream-1 wave pairbase (uniform)
    const int pb2   = pb1 + PAIR_OFF;             // stream-2 wave pairbase (uniform)
    const int sub   = (threadIdx.x >> 4) & 3; // which of the wave's 4 pairs
    const int t     = (pb1 + sub) & 15;       // type; same for both streams

    f32x4 r1, r2;
    if ((pb1 & 15) >= 8) {
        // categorical: 8 wave-uniform scalar loads of u[0]
        const float a0 = u_in[(size_t)(pb1 + 0) * 3];
        const float a1 = u_in[(size_t)(pb1 + 1) * 3];
        const float a2 = u_in[(size_t)(pb1 + 2) * 3];
        const float a3 = u_in[(size_t)(pb1 + 3) * 3];
        const float b0 = u_in[(size_t)(pb2 + 0) * 3];
        const float b1 = u_in[(size_t)(pb2 + 1) * 3];
        const float b2 = u_in[(size_t)(pb2 + 2) * 3];
        const float b3 = u_in[(size_t)(pb2 + 3) * 3];
        const float cv1 = (sub & 2) ? ((sub & 1) ? a3 : a2) : ((sub & 1) ? a1 : a0);
        const float cv2 = (sub & 2) ? ((sub & 1) ? b3 : b2) : ((sub & 1) ? b1 : b0);
        const int idx1 = t * 32 + __float2int_rn(cv1);
        const int idx2 = t * 32 + __float2int_rn(cv2);
        r1 = reinterpret_cast<const f32x4*>(cat_table + (size_t)idx1 * H_)[lane4];
        r2 = reinterpret_cast<const f32x4*>(cat_table + (size_t)idx2 * H_)[lane4];
    } else {
        // numeric: 8 wave-uniform scalar loads of u[1]; conv rows shared (same t)
        const float a0 = u_in[(size_t)(pb1 + 0) * 3 + 1];
        const float a1 = u_in[(size_t)(pb1 + 1) * 3 + 1];
        const float a2 = u_in[(size_t)(pb1 + 2) * 3 + 1];
        const float a3 = u_in[(size_t)(pb1 + 3) * 3 + 1];
        const float b0 = u_in[(size_t)(pb2 + 0) * 3 + 1];
        const float b1 = u_in[(size_t)(pb2 + 1) * 3 + 1];
        const float b2 = u_in[(size_t)(pb2 + 2) * 3 + 1];
        const float b3 = u_in[(size_t)(pb2 + 3) * 3 + 1];
        const float nv1 = (sub & 2) ? ((sub & 1) ? a3 : a2) : ((sub & 1) ? a1 : a0);
        const float nv2 = (sub & 2) ? ((sub & 1) ? b3 : b2) : ((sub & 1) ? b1 : b0);
        const f32x4 wv = reinterpret_cast<const f32x4*>(conv_w + t * H_)[lane4];
        const f32x4 bv = reinterpret_cast<const f32x4*>(conv_b + t * H_)[lane4];
        r1.x = fmaf(nv1, wv.x, bv.x);  r2.x = fmaf(nv2, wv.x, bv.x);
        r1.y = fmaf(nv1, wv.y, bv.y);  r2.y = fmaf(nv2, wv.y, bv.y);
        r1.z = fmaf(nv1, wv.z, bv.z);  r2.z = fmaf(nv2, wv.z, bv.z);
        r1.w = fmaf(nv1, wv.w, bv.w);  r2.w = fmaf(nv2, wv.w, bv.w);
    }
    // two independent, fully coalesced streams (1 KiB/wave each)
    reinterpret_cast<f32x4*>(out)[i]           = r1;
    reinterpret_cast<f32x4*>(out)[i + HALF_V4] = r2;
}

extern "C" void kernel_launch(void* const* d_in, const int* in_sizes, int n_in,
                              void* d_out, int out_size, void* d_ws, size_t ws_size,
                              hipStream_t stream) {
    const float* u_in      = (const float*)d_in[0];
    const float* conv_w    = (const float*)d_in[1];
    const float* conv_b    = (const float*)d_in[2];
    const float* cat_table = (const float*)d_in[3];
    float* out = (float*)d_out;

    // HALF_V4 threads, each writing 2 float4s: 4096 blocks x 1024 threads
    preset_embed_kernel<<<HALF_V4 / 1024, 1024, 0, stream>>>(u_in, conv_w, conv_b, cat_table, out);
}

// Round 8
// 26.296 us; speedup vs baseline: 1.0194x; 1.0194x over previous
//
#include <hip/hip_runtime.h>

// PresetEmbedding: N=2048, L=256, H=64, NT=16, MAXC=32
// out[n][l][h] = (t>=8) ? cat_table[t*32 + round(cat_val)][h]
//                       : num_val * conv_w[t*64+h] + conv_b[t*64+h]
// t = l % 16 (deterministic from index), cat_val = u_in[n][l][0],
// num_val = u_in[n][l][1].
//
// v8 == v6 (best, 26.31 us): one float4 per thread, 256-thread blocks,
// wave-uniform branch + wave-uniform scalar u_in loads (s_load, not VMEM),
// plain coalesced stores. Reverts v7's 2-per-thread/1024-block change
// (-1.9%) . NT stores regressed 48% (R3). Effective BW 5.34 TB/s = ~85% of
// the 6.3 TB/s achievable ceiling -> streaming-write roofline for a 26 us
// mixed read+gather+write dispatch.

#define N_ 2048
#define L_ 256
#define H_ 64

typedef float f32x4 __attribute__((ext_vector_type(4)));

__global__ __launch_bounds__(256) void preset_embed_kernel(
    const float* __restrict__ u_in,      // N*L*3
    const float* __restrict__ conv_w,    // NT*H = 1024
    const float* __restrict__ conv_b,    // NT*H = 1024
    const float* __restrict__ cat_table, // MAXC*NT*H = 512*64
    float* __restrict__ out)             // N*L*H
{
    const int i        = blockIdx.x * blockDim.x + threadIdx.x;  // float4 index
    const int lane4    = i & 15;                  // which float4 within H=64
    const int wid      = threadIdx.x >> 6;        // wave id in block (uniform)
    const int pairbase = blockIdx.x * 16 + wid * 4;  // wave's first pair (uniform)
    const int sub      = (threadIdx.x >> 4) & 3;  // which of the wave's 4 pairs
    const int pair     = pairbase + sub;
    const int t        = pair & 15;               // l % 16

    f32x4 r;
    if ((pairbase & 15) >= 8) {
        // categorical wave: 4 wave-uniform scalar loads of u[0]
        float cv0 = u_in[(size_t)(pairbase + 0) * 3];
        float cv1 = u_in[(size_t)(pairbase + 1) * 3];
        float cv2 = u_in[(size_t)(pairbase + 2) * 3];
        float cv3 = u_in[(size_t)(pairbase + 3) * 3];
        const float cat_val = (sub & 2) ? ((sub & 1) ? cv3 : cv2)
                                        : ((sub & 1) ? cv1 : cv0);
        const int idx = t * 32 + __float2int_rn(cat_val);
        r = reinterpret_cast<const f32x4*>(cat_table + (size_t)idx * H_)[lane4];
    } else {
        // numeric wave: 4 wave-uniform scalar loads of u[1]
        float nv0 = u_in[(size_t)(pairbase + 0) * 3 + 1];
        float nv1 = u_in[(size_t)(pairbase + 1) * 3 + 1];
        float nv2 = u_in[(size_t)(pairbase + 2) * 3 + 1];
        float nv3 = u_in[(size_t)(pairbase + 3) * 3 + 1];
        const float num_val = (sub & 2) ? ((sub & 1) ? nv3 : nv2)
                                        : ((sub & 1) ? nv1 : nv0);
        const f32x4 wv = reinterpret_cast<const f32x4*>(conv_w + t * H_)[lane4];
        const f32x4 bv = reinterpret_cast<const f32x4*>(conv_b + t * H_)[lane4];
        r.x = fmaf(num_val, wv.x, bv.x);
        r.y = fmaf(num_val, wv.y, bv.y);
        r.z = fmaf(num_val, wv.z, bv.z);
        r.w = fmaf(num_val, wv.w, bv.w);
    }
    reinterpret_cast<f32x4*>(out)[i] = r;   // coalesced, 1 KiB per wave
}

extern "C" void kernel_launch(void* const* d_in, const int* in_sizes, int n_in,
                              void* d_out, int out_size, void* d_ws, size_t ws_size,
                              hipStream_t stream) {
    const float* u_in      = (const float*)d_in[0];
    const float* conv_w    = (const float*)d_in[1];
    const float* conv_b    = (const float*)d_in[2];
    const float* cat_table = (const float*)d_in[3];
    float* out = (float*)d_out;

    const int total_v4 = N_ * L_ * (H_ / 4);   // 2,097,152 float4s, one per thread
    preset_embed_kernel<<<total_v4 / 256, 256, 0, stream>>>(u_in, conv_w, conv_b, cat_table, out);
}